// Round 1
// baseline (248.623 us; speedup 1.0000x reference)
//
#include <hip/hip_runtime.h>
#include <math.h>

// Sparsemax via exact Newton root-finding on f(tau) = sum(max(x - tau, 0)) - 1.
// f is piecewise-linear, convex, decreasing; starting at tau0 = max - 1 (f >= 0),
// Newton converges monotonically from the left and terminates exactly once the
// active set stabilizes (typically < 10 iterations for Gaussian rows).
// Matches the reference's 50-iter bisection + renormalize to ~1e-6.

constexpr int D       = 32000;
constexpr int NV4     = D / 4;          // 8000 float4 per row
constexpr int THREADS = 1024;
constexpr int NWAVES  = THREADS / 64;   // 16 waves
constexpr int VPT     = 8;              // float4 per thread: 8*1024 = 8192 >= 8000

__global__ __launch_bounds__(THREADS)
void sparsemax_newton_kernel(const float* __restrict__ X, float* __restrict__ Y) {
    const int row  = blockIdx.x;
    const int tid  = threadIdx.x;
    const int wid  = tid >> 6;
    const int lane = tid & 63;

    const float4* xr = reinterpret_cast<const float4*>(X + (size_t)row * D);
    float4*       yr = reinterpret_cast<float4*>(Y + (size_t)row * D);

    // ---- load the whole row into registers (coalesced, 16B/lane) ----
    float4 r[VPT];
    #pragma unroll
    for (int j = 0; j < VPT; ++j) {
        const int idx = tid + j * THREADS;
        if (idx < NV4) {
            r[j] = xr[idx];
        } else {
            r[j] = make_float4(-INFINITY, -INFINITY, -INFINITY, -INFINITY);
        }
    }

    __shared__ float sa[NWAVES];
    __shared__ float sb[NWAVES];

    // ---- row max ----
    float m = -INFINITY;
    #pragma unroll
    for (int j = 0; j < VPT; ++j) {
        m = fmaxf(m, fmaxf(fmaxf(r[j].x, r[j].y), fmaxf(r[j].z, r[j].w)));
    }
    #pragma unroll
    for (int off = 32; off >= 1; off >>= 1)
        m = fmaxf(m, __shfl_xor(m, off, 64));
    if (lane == 0) sa[wid] = m;
    __syncthreads();
    float rowmax = sa[0];
    #pragma unroll
    for (int w = 1; w < NWAVES; ++w) rowmax = fmaxf(rowmax, sa[w]);

    // ---- Newton iterations, data stays in VGPRs ----
    float tau = rowmax - 1.0f;
    for (int it = 0; it < 60; ++it) {
        float s = 0.0f, c = 0.0f;
        #pragma unroll
        for (int j = 0; j < VPT; ++j) {
            float v;
            v = r[j].x - tau; if (v > 0.0f) { s += v; c += 1.0f; }
            v = r[j].y - tau; if (v > 0.0f) { s += v; c += 1.0f; }
            v = r[j].z - tau; if (v > 0.0f) { s += v; c += 1.0f; }
            v = r[j].w - tau; if (v > 0.0f) { s += v; c += 1.0f; }
        }
        #pragma unroll
        for (int off = 32; off >= 1; off >>= 1) {
            s += __shfl_xor(s, off, 64);
            c += __shfl_xor(c, off, 64);
        }
        __syncthreads();                  // WAR: previous iter's LDS reads done
        if (lane == 0) { sa[wid] = s; sb[wid] = c; }
        __syncthreads();
        float S = 0.0f, C = 0.0f;
        #pragma unroll
        for (int w = 0; w < NWAVES; ++w) { S += sa[w]; C += sb[w]; }
        const float f = S - 1.0f;
        if (f <= 1e-6f) break;            // block-uniform branch
        const float nt = tau + f / C;     // C >= 1 guaranteed (tau < max)
        if (nt == tau) break;             // fp32 fixed point
        tau = nt;
    }

    // ---- final sum at converged tau (recompute, don't store p) ----
    float s = 0.0f;
    #pragma unroll
    for (int j = 0; j < VPT; ++j) {
        s += fmaxf(r[j].x - tau, 0.0f);
        s += fmaxf(r[j].y - tau, 0.0f);
        s += fmaxf(r[j].z - tau, 0.0f);
        s += fmaxf(r[j].w - tau, 0.0f);
    }
    #pragma unroll
    for (int off = 32; off >= 1; off >>= 1) s += __shfl_xor(s, off, 64);
    __syncthreads();                      // WAR on sa
    if (lane == 0) sa[wid] = s;
    __syncthreads();
    float S = 0.0f;
    #pragma unroll
    for (int w = 0; w < NWAVES; ++w) S += sa[w];
    const float inv = 1.0f / S;

    // ---- write p / sum(p), coalesced float4 ----
    #pragma unroll
    for (int j = 0; j < VPT; ++j) {
        const int idx = tid + j * THREADS;
        if (idx < NV4) {
            float4 o;
            o.x = fmaxf(r[j].x - tau, 0.0f) * inv;
            o.y = fmaxf(r[j].y - tau, 0.0f) * inv;
            o.z = fmaxf(r[j].z - tau, 0.0f) * inv;
            o.w = fmaxf(r[j].w - tau, 0.0f) * inv;
            yr[idx] = o;
        }
    }
}

extern "C" void kernel_launch(void* const* d_in, const int* in_sizes, int n_in,
                              void* d_out, int out_size, void* d_ws, size_t ws_size,
                              hipStream_t stream) {
    const float* X = (const float*)d_in[0];
    float*       Y = (float*)d_out;
    const int rows = in_sizes[0] / D;
    sparsemax_newton_kernel<<<rows, THREADS, 0, stream>>>(X, Y);
}

// Round 2
// 195.957 us; speedup vs baseline: 1.2688x; 1.2688x over previous
//
#include <hip/hip_runtime.h>
#include <math.h>

// Sparsemax via Newton on f(tau) = sum(max(x - tau, 0)) - 1, exploiting that
// tau only ever increases from tau0 = rowmax - 1: only elements with
// x > rowmax - 1 can ever be active. For Gaussian rows that's ~6 of 32000,
// so Newton runs on a tiny LDS candidate set with a single wave (no block
// barriers). Block-uniform fallback to full-register Newton if the candidate
// set overflows (correctness for adversarial inputs).

constexpr int D       = 32000;
constexpr int NV4     = D / 4;          // 8000 float4 per row
constexpr int THREADS = 1024;
constexpr int NWAVES  = THREADS / 64;   // 16 waves
constexpr int VPT     = 8;              // float4 per thread: 8*1024 = 8192 >= 8000
constexpr int CAP     = 2048;           // candidate capacity (8 KB LDS)

__global__ __launch_bounds__(THREADS)
void sparsemax_newton_kernel(const float* __restrict__ X, float* __restrict__ Y) {
    const int row  = blockIdx.x;
    const int tid  = threadIdx.x;
    const int wid  = tid >> 6;
    const int lane = tid & 63;

    const float4* xr = reinterpret_cast<const float4*>(X + (size_t)row * D);
    float4*       yr = reinterpret_cast<float4*>(Y + (size_t)row * D);

    __shared__ float sa[NWAVES];
    __shared__ float cand[CAP];
    __shared__ int   cnt;
    __shared__ float s_tau, s_inv;

    if (tid == 0) cnt = 0;

    // ---- load the whole row into registers (coalesced, 16B/lane) ----
    float4 r[VPT];
    #pragma unroll
    for (int j = 0; j < VPT; ++j) {
        const int idx = tid + j * THREADS;
        if (idx < NV4) {
            r[j] = xr[idx];
        } else {
            r[j] = make_float4(-INFINITY, -INFINITY, -INFINITY, -INFINITY);
        }
    }

    // ---- row max ----
    float m = -INFINITY;
    #pragma unroll
    for (int j = 0; j < VPT; ++j)
        m = fmaxf(m, fmaxf(fmaxf(r[j].x, r[j].y), fmaxf(r[j].z, r[j].w)));
    #pragma unroll
    for (int off = 32; off >= 1; off >>= 1)
        m = fmaxf(m, __shfl_xor(m, off, 64));
    if (lane == 0) sa[wid] = m;
    __syncthreads();                         // also orders cnt=0 vs atomics below
    float rowmax = sa[0];
    #pragma unroll
    for (int w = 1; w < NWAVES; ++w) rowmax = fmaxf(rowmax, sa[w]);

    // ---- collect candidates x > rowmax - 1 into LDS ----
    const float thresh = rowmax - 1.0f;
    #pragma unroll
    for (int j = 0; j < VPT; ++j) {
        float v;
        v = r[j].x; if (v > thresh) { int i = atomicAdd(&cnt, 1); if (i < CAP) cand[i] = v; }
        v = r[j].y; if (v > thresh) { int i = atomicAdd(&cnt, 1); if (i < CAP) cand[i] = v; }
        v = r[j].z; if (v > thresh) { int i = atomicAdd(&cnt, 1); if (i < CAP) cand[i] = v; }
        v = r[j].w; if (v > thresh) { int i = atomicAdd(&cnt, 1); if (i < CAP) cand[i] = v; }
    }
    __syncthreads();
    const int K = cnt;

    float tau, inv;
    if (K <= CAP) {
        // ---- single-wave Newton over the candidate set (no block barriers) ----
        if (wid == 0) {
            float t = thresh;
            for (int it = 0; it < 60; ++it) {
                float s = 0.0f, c = 0.0f;
                for (int i = lane; i < K; i += 64) {
                    const float v = cand[i] - t;
                    if (v > 0.0f) { s += v; c += 1.0f; }
                }
                #pragma unroll
                for (int off = 32; off >= 1; off >>= 1) {
                    s += __shfl_xor(s, off, 64);
                    c += __shfl_xor(c, off, 64);
                }
                const float f = s - 1.0f;
                if (f <= 1e-6f) break;
                const float nt = t + f / c;   // c >= 1 (rowmax is always active)
                if (nt == t) break;
                t = nt;
            }
            float s = 0.0f;
            for (int i = lane; i < K; i += 64) s += fmaxf(cand[i] - t, 0.0f);
            #pragma unroll
            for (int off = 32; off >= 1; off >>= 1) s += __shfl_xor(s, off, 64);
            if (lane == 0) { s_tau = t; s_inv = 1.0f / s; }
        }
        __syncthreads();
        tau = s_tau;
        inv = s_inv;
    } else {
        // ---- fallback: block-wide Newton over full register data ----
        __shared__ float fa[NWAVES], fb[NWAVES];
        tau = thresh;
        for (int it = 0; it < 60; ++it) {
            float s = 0.0f, c = 0.0f;
            #pragma unroll
            for (int j = 0; j < VPT; ++j) {
                float v;
                v = r[j].x - tau; if (v > 0.0f) { s += v; c += 1.0f; }
                v = r[j].y - tau; if (v > 0.0f) { s += v; c += 1.0f; }
                v = r[j].z - tau; if (v > 0.0f) { s += v; c += 1.0f; }
                v = r[j].w - tau; if (v > 0.0f) { s += v; c += 1.0f; }
            }
            #pragma unroll
            for (int off = 32; off >= 1; off >>= 1) {
                s += __shfl_xor(s, off, 64);
                c += __shfl_xor(c, off, 64);
            }
            __syncthreads();
            if (lane == 0) { fa[wid] = s; fb[wid] = c; }
            __syncthreads();
            float S = 0.0f, C = 0.0f;
            #pragma unroll
            for (int w = 0; w < NWAVES; ++w) { S += fa[w]; C += fb[w]; }
            const float f = S - 1.0f;
            if (f <= 1e-6f) break;
            const float nt = tau + f / C;
            if (nt == tau) break;
            tau = nt;
        }
        float s = 0.0f;
        #pragma unroll
        for (int j = 0; j < VPT; ++j) {
            s += fmaxf(r[j].x - tau, 0.0f);
            s += fmaxf(r[j].y - tau, 0.0f);
            s += fmaxf(r[j].z - tau, 0.0f);
            s += fmaxf(r[j].w - tau, 0.0f);
        }
        #pragma unroll
        for (int off = 32; off >= 1; off >>= 1) s += __shfl_xor(s, off, 64);
        __syncthreads();
        if (lane == 0) fa[wid] = s;
        __syncthreads();
        float S = 0.0f;
        #pragma unroll
        for (int w = 0; w < NWAVES; ++w) S += fa[w];
        inv = 1.0f / S;
    }

    // ---- write p = max(x - tau, 0) * inv, coalesced float4 ----
    #pragma unroll
    for (int j = 0; j < VPT; ++j) {
        const int idx = tid + j * THREADS;
        if (idx < NV4) {
            float4 o;
            o.x = fmaxf(r[j].x - tau, 0.0f) * inv;
            o.y = fmaxf(r[j].y - tau, 0.0f) * inv;
            o.z = fmaxf(r[j].z - tau, 0.0f) * inv;
            o.w = fmaxf(r[j].w - tau, 0.0f) * inv;
            yr[idx] = o;
        }
    }
}

extern "C" void kernel_launch(void* const* d_in, const int* in_sizes, int n_in,
                              void* d_out, int out_size, void* d_ws, size_t ws_size,
                              hipStream_t stream) {
    const float* X = (const float*)d_in[0];
    float*       Y = (float*)d_out;
    const int rows = in_sizes[0] / D;
    sparsemax_newton_kernel<<<rows, THREADS, 0, stream>>>(X, Y);
}